// Round 2
// baseline (605.853 us; speedup 1.0000x reference)
//
#include <hip/hip_runtime.h>

#define VOCAB 512
#define EMB   128
#define HID   64
#define BATCH 256
#define TLEN  1024
#define CH    8               // steps per chunk (smaller: keep unrolled bodies in I-cache)
#define NCH   (TLEN / CH)     // 128 chunks
#define RS    128             // ring depth in steps
#define RCH   (RS / CH)       // 16 chunks per ring

__device__ __forceinline__ float fast_tanh(float x) {
    // tanh(x) = 1 - 2/(exp(2x)+1); exact at both saturated ends.
    float e = __expf(2.0f * x);
    return 1.0f - 2.0f / (e + 1.0f);
}

// LDS-only fence: drains DS queue WITHOUT vmcnt -> global prefetches live on.
__device__ __forceinline__ void lds_fence() {
    asm volatile("s_waitcnt lgkmcnt(0)" ::: "memory");
}
__device__ __forceinline__ void compiler_fence() {
    asm volatile("" ::: "memory");
}
__device__ __forceinline__ void nap() { __builtin_amdgcn_s_sleep(1); }

// dot(W_row[lane][:], h) where h lives one-element-per-lane in hv.
// R9: broadcast via v_readlane -> SGPR -> scalar-operand v_fmac
// (VOP2 permits one SGPR source). ZERO LDS traffic for the broadcast:
// the old dot64_lds pushed 16 KiB/step/wave through the shared LDS return
// network (3 waves x 16 ds_read_b128 broadcast = the 742 cyc/step wall);
// readlane runs on each wave's PRIVATE SIMD VALU pipe instead.
__device__ __forceinline__ float dot64_rl(float hv, const float* w, float init) {
    const int hb = __float_as_int(hv);
    float a0 = init, a1 = 0.f, a2 = 0.f, a3 = 0.f;
    #pragma unroll
    for (int j = 0; j < 64; j += 4) {
        a0 = fmaf(w[j + 0], __int_as_float(__builtin_amdgcn_readlane(hb, j + 0)), a0);
        a1 = fmaf(w[j + 1], __int_as_float(__builtin_amdgcn_readlane(hb, j + 1)), a1);
        a2 = fmaf(w[j + 2], __int_as_float(__builtin_amdgcn_readlane(hb, j + 2)), a2);
        a3 = fmaf(w[j + 3], __int_as_float(__builtin_amdgcn_readlane(hb, j + 3)), a3);
    }
    return (a0 + a1) + (a2 + a3);
}

// ---------------------------------------------------------------------------
// Kernel 1: P0[v][i] = sum_e emb[v][e]*Wih0[i][e] + bih0[i] + bhh0[i]  (fp32)
// ---------------------------------------------------------------------------
__global__ void __launch_bounds__(64) p0_kernel(
    const float* __restrict__ emb,
    const float* __restrict__ wih0,
    const float* __restrict__ bih0,
    const float* __restrict__ bhh0,
    float* __restrict__ P0)
{
    const int v = blockIdx.x;
    const int i = threadIdx.x;
    const float4* er = (const float4*)(emb  + v * EMB);
    const float4* wr = (const float4*)(wih0 + i * EMB);
    float a0 = 0.f, a1 = 0.f, a2 = 0.f, a3 = 0.f;
    #pragma unroll
    for (int k = 0; k < EMB / 4; ++k) {
        float4 e4 = er[k];
        float4 w4 = wr[k];
        a0 = fmaf(e4.x, w4.x, a0);
        a1 = fmaf(e4.y, w4.y, a1);
        a2 = fmaf(e4.z, w4.z, a2);
        a3 = fmaf(e4.w, w4.w, a3);
    }
    P0[v * HID + i] = (a0 + a1) + (a2 + a3) + bih0[i] + bhh0[i];
}

// ---------------------------------------------------------------------------
// Kernel 2: decoupled 3-wave pipeline, register-resident recurrent state.
//   wave0: h0[t] = tanh(P0[x[t]] + Whh0 h0[t-1])   h0 in VGPR (lane = index)
//   wave1: p1[t] = b1 + Wih1 h0[t]                  h0 read from ring (1 b32)
//   wave2: h1[t] = tanh(p1[t] + Whh1 h1[t-1])       h1 never touches LDS
// Per-step LDS: wave0 1 write, wave1 1 read + 1 write, wave2 1 read.
// ---------------------------------------------------------------------------
__global__ void __launch_bounds__(192, 1) rnn_kernel(
    const int*   __restrict__ xs,
    const float* __restrict__ P0,
    const float* __restrict__ Whh0,
    const float* __restrict__ Wih1,
    const float* __restrict__ Whh1,
    const float* __restrict__ bih1,
    const float* __restrict__ bhh1,
    const float* __restrict__ W1,
    const float* __restrict__ b1,
    const float* __restrict__ W2,
    const float* __restrict__ b2,
    float*       __restrict__ out)
{
    __shared__ float h0ring[RS][HID];   // 32 KiB
    __shared__ float p1ring[RS][HID];   // 32 KiB
    __shared__ int   flags[3];

    const int b    = blockIdx.x;
    const int tid  = threadIdx.x;
    const int wv   = tid >> 6;
    const int lane = tid & 63;

    const int* xrow = xs + b * TLEN;
    // vz == 0, but opaque to uniformity analysis -> forces VECTOR loads
    // (vmcnt path) for the x reads instead of s_load (lgkmcnt path).
    const int vz = (int)__builtin_amdgcn_mbcnt_lo(0u, 0u);

    if (tid < 3) flags[tid] = 0;
    __syncthreads();                     // the ONLY barrier in the kernel

    // Per-lane weight row -> 64 scalar VGPRs, loop-invariant.
    const float* wmat = (wv == 0) ? Whh0 : (wv == 1) ? Wih1 : Whh1;
    float w[64];
    {
        const float4* wr = (const float4*)(wmat + lane * HID);
        #pragma unroll
        for (int k = 0; k < 16; ++k) {
            float4 u = wr[k];
            w[4 * k + 0] = u.x;
            w[4 * k + 1] = u.y;
            w[4 * k + 2] = u.z;
            w[4 * k + 3] = u.w;
        }
    }

    volatile int* vf = (volatile int*)flags;

    if (wv == 0) {
        // ---- layer-0 recurrence, chunk-ahead VGPR prefetch pipeline ----
        int   xv_old[CH];    // x indices of chunk k+1
        float a_old[CH];     // P0 rows for the CURRENT chunk
        #pragma unroll
        for (int i = 0; i < CH; ++i)
            xv_old[i] = xrow[CH + i + vz] & (VOCAB - 1);    // x of chunk 1
        #pragma unroll
        for (int i = 0; i < CH; ++i)
            a_old[i] = P0[(xrow[i + vz] & (VOCAB - 1)) * HID + lane]; // chunk 0

        float hv = 0.f;                  // h0[-1] = 0, lives in a VGPR
        #pragma unroll 1
        for (int k = 0; k < NCH; ++k) {
            if (k >= RCH) {                       // slot reuse guard
                while (vf[1] < k - (RCH - 1)) nap();
                compiler_fence();
            }
            // prefetch x of chunk k+2 and gather P0 rows of chunk k+1 —
            // all vector loads (vmcnt), consumed a full chunk later
            const int  c2  = (k + 2 < NCH) ? (k + 2) : (NCH - 1);
            const int* xp  = xrow + c2 * CH;
            int   xv_new[CH];
            float a_new[CH];
            #pragma unroll
            for (int i = 0; i < CH; ++i)
                xv_new[i] = xp[i + vz] & (VOCAB - 1);
            #pragma unroll
            for (int i = 0; i < CH; ++i)
                a_new[i] = P0[xv_old[i] * HID + lane];

            const int base = (k & (RCH - 1)) * CH;
            #pragma unroll
            for (int i = 0; i < CH; ++i) {
                float z = dot64_rl(hv, w, a_old[i]);
                hv = fast_tanh(z);
                h0ring[base + i][lane] = hv;      // only LDS op per step
            }
            lds_fence();                          // DS queue only, NOT vmcnt
            if (lane == 0) vf[0] = k + 1;

            #pragma unroll
            for (int i = 0; i < CH; ++i) { a_old[i] = a_new[i]; xv_old[i] = xv_new[i]; }
        }
    } else if (wv == 1) {
        // ---- layer-1 input projection (no recurrence: pure throughput) ----
        const float b1s = bih1[lane] + bhh1[lane];
        #pragma unroll 1
        for (int k = 0; k < NCH; ++k) {
            while (vf[0] < k + 1) nap();
            if (k >= RCH) { while (vf[2] < k - (RCH - 1)) nap(); }
            compiler_fence();
            const int base = (k & (RCH - 1)) * CH;
            float hvv[CH];                        // bulk per-lane b32 reads
            #pragma unroll
            for (int i = 0; i < CH; ++i) hvv[i] = h0ring[base + i][lane];
            #pragma unroll
            for (int i = 0; i < CH; ++i)
                p1ring[base + i][lane] = dot64_rl(hvv[i], w, b1s);
            lds_fence();
            if (lane == 0) vf[1] = k + 1;
        }
    } else {
        // ---- layer-1 recurrence: h1 fully register-resident ----
        float h1v = 0.f;
        #pragma unroll 1
        for (int k = 0; k < NCH; ++k) {
            while (vf[1] < k + 1) nap();
            compiler_fence();
            const int base = (k & (RCH - 1)) * CH;
            float p[CH];                          // bulk chunk prefetch (DS)
            #pragma unroll
            for (int i = 0; i < CH; ++i) p[i] = p1ring[base + i][lane];
            #pragma unroll
            for (int i = 0; i < CH; ++i) {
                float z = dot64_rl(h1v, w, p[i]);
                h1v = fast_tanh(z);
            }
            lds_fence();                          // p1 reads consumed
            if (lane == 0) vf[2] = k + 1;
        }
        // ---- MLP head: y = relu(h1 @ W1^T + b1) @ W2^T + b2 ----
        // h1 is per-lane in h1v; broadcast with readlane (valid in all lanes).
        const int hb = __float_as_int(h1v);
        float r = 0.f;
        if (lane < 32) {
            float acc = b1[lane];
            const float* w1r = W1 + lane * HID;
            #pragma unroll
            for (int j = 0; j < HID; ++j)
                acc = fmaf(w1r[j],
                           __int_as_float(__builtin_amdgcn_readlane(hb, j)), acc);
            r = fmaxf(acc, 0.f) * W2[lane];
        }
        #pragma unroll
        for (int off = 32; off > 0; off >>= 1) r += __shfl_down(r, off);
        if (lane == 0) out[b] = r + b2[0];
    }
}

extern "C" void kernel_launch(void* const* d_in, const int* in_sizes, int n_in,
                              void* d_out, int out_size, void* d_ws, size_t ws_size,
                              hipStream_t stream)
{
    const int*   x    = (const int*)d_in[0];
    const float* emb  = (const float*)d_in[1];
    const float* Wih0 = (const float*)d_in[2];
    const float* Whh0 = (const float*)d_in[3];
    const float* bih0 = (const float*)d_in[4];
    const float* bhh0 = (const float*)d_in[5];
    const float* Wih1 = (const float*)d_in[6];
    const float* Whh1 = (const float*)d_in[7];
    const float* bih1 = (const float*)d_in[8];
    const float* bhh1 = (const float*)d_in[9];
    const float* W1   = (const float*)d_in[10];
    const float* b1   = (const float*)d_in[11];
    const float* W2   = (const float*)d_in[12];
    const float* b2   = (const float*)d_in[13];

    float* P0 = (float*)d_ws;   // 512*64*4 = 128 KiB scratch

    hipLaunchKernelGGL(p0_kernel, dim3(VOCAB), dim3(HID), 0, stream,
                       emb, Wih0, bih0, bhh0, P0);
    hipLaunchKernelGGL(rnn_kernel, dim3(BATCH), dim3(192), 0, stream,
                       x, P0, Whh0, Wih1, Whh1, bih1, bhh1,
                       W1, b1, W2, b2, (float*)d_out);
}

// Round 3
// 441.618 us; speedup vs baseline: 1.3719x; 1.3719x over previous
//
#include <hip/hip_runtime.h>

#define VOCAB 512
#define EMB   128
#define HID   64
#define BATCH 256
#define TLEN  1024
#define CH    8               // steps per chunk
#define NCH   (TLEN / CH)     // 128 chunks
#define RS    128             // ring depth in steps
#define RCH   (RS / CH)       // 16 chunks per ring

typedef float v2f __attribute__((ext_vector_type(2)));

__device__ __forceinline__ float fast_tanh(float x) {
    // tanh(x) = 1 - 2/(exp(2x)+1); exact at both saturated ends.
    float e = __expf(2.0f * x);
    return 1.0f - 2.0f / (e + 1.0f);
}

// LDS-only fence: drains DS queue WITHOUT vmcnt -> global prefetches live on.
__device__ __forceinline__ void lds_fence() {
    asm volatile("s_waitcnt lgkmcnt(0)" ::: "memory");
}
__device__ __forceinline__ void compiler_fence() {
    asm volatile("" ::: "memory");
}
__device__ __forceinline__ void nap() { __builtin_amdgcn_s_sleep(1); }

// Broadcast-load one 64-float LDS row into 16 float4 registers.
// All lanes read the same row (conflict-free broadcast); compiler emits
// 16x ds_read_b128 with fine-grained lgkmcnt before each use.
__device__ __forceinline__ void bcast_load(float4* hb, const float* row) {
    const float4* hp = (const float4*)row;
    #pragma unroll
    for (int q = 0; q < 16; ++q) hb[q] = hp[q];
}

// dot(w_row[lane][:], h) from a register-resident h broadcast (hb[16]).
// Four 8-deep v2f accumulator chains (R5 structure, register source).
__device__ __forceinline__ float dot64_reg(const float4* hb, const v2f* w,
                                           float init) {
    v2f a0 = v2f{init, 0.f}, a1 = v2f{0.f, 0.f};
    v2f a2 = v2f{0.f, 0.f},  a3 = v2f{0.f, 0.f};
    #pragma unroll
    for (int q = 0; q < 8; ++q) {
        float4 u = hb[2 * q];
        float4 v = hb[2 * q + 1];
        a0 = __builtin_elementwise_fma(v2f{u.x, u.y}, w[4 * q + 0], a0);
        a1 = __builtin_elementwise_fma(v2f{u.z, u.w}, w[4 * q + 1], a1);
        a2 = __builtin_elementwise_fma(v2f{v.x, v.y}, w[4 * q + 2], a2);
        a3 = __builtin_elementwise_fma(v2f{v.z, v.w}, w[4 * q + 3], a3);
    }
    return ((a0.x + a0.y) + (a1.x + a1.y)) + ((a2.x + a2.y) + (a3.x + a3.y));
}

// ---------------------------------------------------------------------------
// Kernel 1: P0[v][i] = sum_e emb[v][e]*Wih0[i][e] + bih0[i] + bhh0[i]  (fp32)
// ---------------------------------------------------------------------------
__global__ void __launch_bounds__(64) p0_kernel(
    const float* __restrict__ emb,
    const float* __restrict__ wih0,
    const float* __restrict__ bih0,
    const float* __restrict__ bhh0,
    float* __restrict__ P0)
{
    const int v = blockIdx.x;
    const int i = threadIdx.x;
    const float4* er = (const float4*)(emb  + v * EMB);
    const float4* wr = (const float4*)(wih0 + i * EMB);
    float a0 = 0.f, a1 = 0.f, a2 = 0.f, a3 = 0.f;
    #pragma unroll
    for (int k = 0; k < EMB / 4; ++k) {
        float4 e4 = er[k];
        float4 w4 = wr[k];
        a0 = fmaf(e4.x, w4.x, a0);
        a1 = fmaf(e4.y, w4.y, a1);
        a2 = fmaf(e4.z, w4.z, a2);
        a3 = fmaf(e4.w, w4.w, a3);
    }
    P0[v * HID + i] = (a0 + a1) + (a2 + a3) + bih0[i] + bhh0[i];
}

// ---------------------------------------------------------------------------
// Kernel 2 (R10): TWO-wave pipeline. R9 post-mortem: readlane->SGPR->VALU
// hazard stalls made the register broadcast SLOWER (542us). R8's wall was
// 48 broadcast ds_read_b128/step from 3 waves sharing one LDS pipe, with
// the recurrent RAW read-back queued behind them. Fix: merge the
// non-recurrent p1 projection into the layer-1 wave; its dot is independent
// of h1, so it executes INSIDE the h1 write->read-back latency window.
//   wave0: h0[t] = tanh(P0[x[t]] + Whh0 h0[t-1])       16 b128/step
//   wave1: p = b1 + Wih1 h0[t]  (h0 prefetched 1 step ahead, no latency)
//          h1[t] = tanh(p + Whh1 h1[t-1])               32 b128/step
// Total LDS broadcast traffic: 32+16 = 48 -> 48? No: 16 (w0) + 32 (w1) = 48
// minus wave1's old separate 16 = net 2/3 of R8, and only ONE flag chain.
// ---------------------------------------------------------------------------
__global__ void __launch_bounds__(128, 1) rnn_kernel(
    const int*   __restrict__ xs,
    const float* __restrict__ P0,
    const float* __restrict__ Whh0,
    const float* __restrict__ Wih1,
    const float* __restrict__ Whh1,
    const float* __restrict__ bih1,
    const float* __restrict__ bhh1,
    const float* __restrict__ W1,
    const float* __restrict__ b1,
    const float* __restrict__ W2,
    const float* __restrict__ b2,
    float*       __restrict__ out)
{
    __shared__ float h0ring[RS][HID];   // 32 KiB
    __shared__ float h1s[HID];          // single h1 handoff row
    __shared__ int   flags[2];

    const int b    = blockIdx.x;
    const int tid  = threadIdx.x;
    const int wv   = tid >> 6;
    const int lane = tid & 63;

    const int* xrow = xs + b * TLEN;
    // vz == 0, but opaque to uniformity analysis -> forces VECTOR loads
    // (vmcnt path) for the x reads instead of s_load (lgkmcnt path).
    const int vz = (int)__builtin_amdgcn_mbcnt_lo(0u, 0u);

    if (tid < 2) flags[tid] = 0;
    __syncthreads();                     // the ONLY barrier in the kernel

    volatile int* vf = (volatile int*)flags;

    if (wv == 0) {
        // ---- layer-0 recurrence ----
        v2f w[32];
        {
            const float4* wr = (const float4*)(Whh0 + lane * HID);
            #pragma unroll
            for (int k = 0; k < 16; ++k) {
                float4 u = wr[k];
                w[2 * k]     = v2f{u.x, u.y};
                w[2 * k + 1] = v2f{u.z, u.w};
            }
        }
        int   xv_old[CH];    // x indices of chunk k+1
        float a_old[CH];     // P0 rows for the CURRENT chunk
        #pragma unroll
        for (int i = 0; i < CH; ++i)
            xv_old[i] = xrow[CH + i + vz] & (VOCAB - 1);
        #pragma unroll
        for (int i = 0; i < CH; ++i)
            a_old[i] = P0[(xrow[i + vz] & (VOCAB - 1)) * HID + lane];

        float4 hb[16];                    // h0[t-1] broadcast, reg-resident
        #pragma unroll
        for (int q = 0; q < 16; ++q) hb[q] = float4{0.f, 0.f, 0.f, 0.f};

        #pragma unroll 1
        for (int k = 0; k < NCH; ++k) {
            if (k >= RCH) {                       // slot reuse guard
                while (vf[1] < k - (RCH - 1)) nap();
                compiler_fence();
            }
            const int  c2  = (k + 2 < NCH) ? (k + 2) : (NCH - 1);
            const int* xp  = xrow + c2 * CH;
            int   xv_new[CH];
            float a_new[CH];
            #pragma unroll
            for (int i = 0; i < CH; ++i)
                xv_new[i] = xp[i + vz] & (VOCAB - 1);
            #pragma unroll
            for (int i = 0; i < CH; ++i)
                a_new[i] = P0[xv_old[i] * HID + lane];

            const int base = (k & (RCH - 1)) * CH;
            #pragma unroll
            for (int i = 0; i < CH; ++i) {
                float z  = dot64_reg(hb, w, a_old[i]);
                float hv = fast_tanh(z);
                h0ring[base + i][lane] = hv;      // publish + self
                bcast_load(hb, h0ring[base + i]); // RAW read-back (in-order DS)
            }
            lds_fence();
            if (lane == 0) vf[0] = k + 1;

            #pragma unroll
            for (int i = 0; i < CH; ++i) { a_old[i] = a_new[i]; xv_old[i] = xv_new[i]; }
        }
    } else {
        // ---- merged: p1 projection + layer-1 recurrence + MLP head ----
        v2f w1r[32], w2r[32];
        {
            const float4* p1 = (const float4*)(Wih1 + lane * HID);
            const float4* p2 = (const float4*)(Whh1 + lane * HID);
            #pragma unroll
            for (int k = 0; k < 16; ++k) {
                float4 u = p1[k];
                w1r[2 * k]     = v2f{u.x, u.y};
                w1r[2 * k + 1] = v2f{u.z, u.w};
                float4 v = p2[k];
                w2r[2 * k]     = v2f{v.x, v.y};
                w2r[2 * k + 1] = v2f{v.z, v.w};
            }
        }
        const float b1s = bih1[lane] + bhh1[lane];

        float4 h0b[16];                   // h0[t] broadcast (prefetched)
        float4 h1b[16];                   // h1[t-1] broadcast
        #pragma unroll
        for (int q = 0; q < 16; ++q) h1b[q] = float4{0.f, 0.f, 0.f, 0.f};

        #pragma unroll 1
        for (int k = 0; k < NCH; ++k) {
            while (vf[0] < k + 1) nap();
            compiler_fence();
            const int base = (k & (RCH - 1)) * CH;
            bcast_load(h0b, h0ring[base]);        // step-0 load (chunk ready)
            #pragma unroll
            for (int i = 0; i < CH; ++i) {
                // dot1 independent of h1 -> executes during h1b flight
                float p  = dot64_reg(h0b, w1r, b1s);
                float z  = dot64_reg(h1b, w2r, p);
                float hv = fast_tanh(z);
                // issue next h0 read FIRST (h0b regs now dead) so the
                // lgkmcnt wait before next dot1 leaves h1b outstanding
                if (i < CH - 1) bcast_load(h0b, h0ring[base + i + 1]);
                h1s[lane] = hv;
                bcast_load(h1b, h1s);             // RAW read-back
            }
            lds_fence();
            if (lane == 0) vf[1] = k + 1;
        }
        // ---- MLP head: y = relu(h1 @ W1^T + b1) @ W2^T + b2 ----
        float r = 0.f;
        if (lane < 32) {
            float acc = b1[lane];
            const float* w1row = W1 + lane * HID;
            const float* hN    = h1s;             // h1[1023]
            #pragma unroll
            for (int j = 0; j < HID; ++j) acc = fmaf(w1row[j], hN[j], acc);
            r = fmaxf(acc, 0.f) * W2[lane];
        }
        #pragma unroll
        for (int off = 32; off > 0; off >>= 1) r += __shfl_down(r, off);
        if (lane == 0) out[b] = r + b2[0];
    }
}

extern "C" void kernel_launch(void* const* d_in, const int* in_sizes, int n_in,
                              void* d_out, int out_size, void* d_ws, size_t ws_size,
                              hipStream_t stream)
{
    const int*   x    = (const int*)d_in[0];
    const float* emb  = (const float*)d_in[1];
    const float* Wih0 = (const float*)d_in[2];
    const float* Whh0 = (const float*)d_in[3];
    const float* bih0 = (const float*)d_in[4];
    const float* bhh0 = (const float*)d_in[5];
    const float* Wih1 = (const float*)d_in[6];
    const float* Whh1 = (const float*)d_in[7];
    const float* bih1 = (const float*)d_in[8];
    const float* bhh1 = (const float*)d_in[9];
    const float* W1   = (const float*)d_in[10];
    const float* b1   = (const float*)d_in[11];
    const float* W2   = (const float*)d_in[12];
    const float* b2   = (const float*)d_in[13];

    float* P0 = (float*)d_ws;   // 512*64*4 = 128 KiB scratch

    hipLaunchKernelGGL(p0_kernel, dim3(VOCAB), dim3(HID), 0, stream,
                       emb, Wih0, bih0, bhh0, P0);
    hipLaunchKernelGGL(rnn_kernel, dim3(BATCH), dim3(128), 0, stream,
                       x, P0, Whh0, Wih1, Whh1, bih1, bhh1,
                       W1, b1, W2, b2, (float*)d_out);
}